// Round 7
// baseline (293.042 us; speedup 1.0000x reference)
//
#include <hip/hip_runtime.h>
#include <math.h>

#define BB 4
#define SS 2048
#define DD 768
#define HH 12
#define DEPTH 64
#define M_TOTAL (BB * SS)  // 8192
#define WSZ (DD * DD)      // 589824

typedef __attribute__((ext_vector_type(8))) short bf16x8;
typedef __attribute__((ext_vector_type(16))) float f32x16;
typedef __attribute__((ext_vector_type(4))) float f32x4;
typedef __attribute__((ext_vector_type(4))) unsigned short us4;
typedef __attribute__((ext_vector_type(2))) unsigned int u32x2;
typedef __attribute__((ext_vector_type(4))) unsigned int u32x4;

// fp32 -> bf16, round-half-up (2 ops); inputs are finite
__device__ __forceinline__ unsigned short f2b(float f) {
  unsigned u = __builtin_bit_cast(unsigned, f);
  return (unsigned short)((u + 0x8000u) >> 16);
}

// pack two fp32 -> bf16x2 (lo, hi) via v_perm_b32: 3 VALU total
__device__ __forceinline__ unsigned pkrnd(float lo, float hi) {
  unsigned a = __builtin_bit_cast(unsigned, lo) + 0x8000u;
  unsigned b = __builtin_bit_cast(unsigned, hi) + 0x8000u;
  return __builtin_amdgcn_perm(b, a, 0x07060302);  // {b.hi16, a.hi16}
}

__device__ __forceinline__ us4 f2b4(float a, float b, float c, float d) {
  unsigned lo = pkrnd(a, b), hi = pkrnd(c, d);
  us4 t;
  t.x = (unsigned short)lo; t.y = (unsigned short)(lo >> 16);
  t.z = (unsigned short)hi; t.w = (unsigned short)(hi >> 16);
  return t;
}

// single-instruction pack: {lo16: bf16(a), hi16: bf16(b)}
__device__ __forceinline__ unsigned cvtpk(float a, float b) {
  unsigned d;
  asm("v_cvt_pk_bf16_f32 %0, %1, %2" : "=v"(d) : "v"(a), "v"(b));
  return d;
}

// v_permlane32_swap_b32: returns {a.lo|b.lo, a.hi|b.hi}
__device__ __forceinline__ u32x2 permswap(unsigned a, unsigned b) {
  auto r = __builtin_amdgcn_permlane32_swap(a, b, false, false);
  u32x2 out;
  out.x = r[0];
  out.y = r[1];
  return out;
}

__device__ __forceinline__ float fexp2(float x) {
  return __builtin_amdgcn_exp2f(x);
}

// async global->LDS, 16B per lane; lds dest = wave-uniform base + lane*16
__device__ __forceinline__ void gl16(const void* g, void* l) {
  __builtin_amdgcn_global_load_lds(
      (const __attribute__((address_space(1))) unsigned int*)g,
      (__attribute__((address_space(3))) unsigned int*)l, 16, 0, 0);
}

// ---------------------------------------------------------------------------
// Prep: fp32 -> bf16 for the 4 WEIGHT matrices only (activations are now
// converted in-flight inside proj_qkv's A-staging). 4 x 576 = 2304 blocks.
// ---------------------------------------------------------------------------
__global__ __launch_bounds__(256) void prep(
    const float* __restrict__ s0, const float* __restrict__ s1,
    const float* __restrict__ s2, const float* __restrict__ s3,
    unsigned short* __restrict__ d0, unsigned short* __restrict__ d1,
    unsigned short* __restrict__ d2, unsigned short* __restrict__ d3) {
  int b = blockIdx.x;
  int mode = b / 576, lb = b - mode * 576;
  const float* s;
  unsigned short* d;
  if (mode == 0) { s = s0; d = d0; }
  else if (mode == 1) { s = s1; d = d1; }
  else if (mode == 2) { s = s2; d = d2; }
  else { s = s3; d = d3; }
  int idx = (lb * 256 + threadIdx.x) * 4;
  float4 f = *(const float4*)(s + idx);
  *(us4*)(d + idx) = f2b4(f.x, f.y, f.z, f.w);
}

// ---------------------------------------------------------------------------
// QKV projection, fused activation conversion: A-side reads fp32 activations
// directly (reg-staged: 4x float4 load -> pkrnd -> ds_write_b128), B-side
// (bf16 weights from prep) keeps global_load_lds. 128x128 tile, BK=32.
// Fragment-major outputs (QF/KF/VF), epilogue through LDS transpose tile:
//   QF/KF[bh][sblk(64)][ks(4)][lane2(64)][j(8)]
//   VF[bh][sblk(64)][ntv(2)][ks2(2)][lane2(64)][j(8)]
// Q scaled by 0.125*log2(e) in the epilogue (softmax scale folded).
// XCD-aware bijective swizzle (384 blocks per z).
// ---------------------------------------------------------------------------
__global__ __launch_bounds__(256) void proj_qkv(
    const float* __restrict__ qf32, const float* __restrict__ kf32,
    const float* __restrict__ vf32, const unsigned short* __restrict__ wqb,
    const unsigned short* __restrict__ wkb, const unsigned short* __restrict__ wvb,
    unsigned short* __restrict__ QF, unsigned short* __restrict__ KF,
    unsigned short* __restrict__ VF) {
  const int mode = blockIdx.z;
  const float* X;
  const unsigned short* W;
  if (mode == 0) { X = qf32; W = wqb; }
  else if (mode == 1) { X = kf32; W = wkb; }
  else { X = vf32; W = wvb; }

  // union: As/Bs (16 KB) live during K-loop; Ts (34816 B) in epilogue
  __shared__ __align__(16) char sm[34816];
  unsigned short* As = (unsigned short*)sm;
  unsigned short* Bs = (unsigned short*)(sm + 8192);
  unsigned short* Ts = (unsigned short*)sm;  // [128][136]

  const int tid = threadIdx.x;
  const int lane = tid & 63, w_ = tid >> 6;
  const int lr = lane & 15, quad = lane >> 4;
  const int wm = (w_ & 1) * 64, wn = (w_ >> 1) * 64;
  // bijective XCD swizzle (384 blocks per z, 384%8==0)
  const int lin = blockIdx.y * 64 + blockIdx.x;
  const int nlin = (lin & 7) * 48 + (lin >> 3);
  const int m0 = (nlin / 6) * 128, n0 = (nlin % 6) * 128;
  // B-staging coords (gl16)
  const int grow = lane >> 2, gcol = (lane & 3) * 8;
  // A-staging coords (reg-staged fp32->bf16): 2 threads per row, 16 elems ea
  const int arow = tid >> 1, acb = (tid & 1) * 16;

  f32x4 acc[4][4];
#pragma unroll
  for (int mt = 0; mt < 4; ++mt)
#pragma unroll
    for (int nt = 0; nt < 4; ++nt) acc[mt][nt] = (f32x4){0.f, 0.f, 0.f, 0.f};

  const float* arow_base = X + (size_t)(m0 + arow) * DD + acb;

  for (int k0 = 0; k0 < DD; k0 += 32) {
    // issue fp32 A loads early (before the barrier) — regs, no LDS hazard
    float4 av0 = *(const float4*)(arow_base + k0);
    float4 av1 = *(const float4*)(arow_base + k0 + 4);
    float4 av2 = *(const float4*)(arow_base + k0 + 8);
    float4 av3 = *(const float4*)(arow_base + k0 + 12);
    __syncthreads();  // prev iter's LDS reads done
#pragma unroll
    for (int i = 0; i < 2; ++i) {
      int c = 4 * i + w_;
      int row = c * 16 + grow;
      gl16(W + (size_t)(n0 + row) * DD + k0 + gcol, (char*)Bs + c * 1024);
    }
    // convert + write A tile (32B per thread = 2x b128)
    u32x4 p0, p1;
    p0.x = pkrnd(av0.x, av0.y); p0.y = pkrnd(av0.z, av0.w);
    p0.z = pkrnd(av1.x, av1.y); p0.w = pkrnd(av1.z, av1.w);
    p1.x = pkrnd(av2.x, av2.y); p1.y = pkrnd(av2.z, av2.w);
    p1.z = pkrnd(av3.x, av3.y); p1.w = pkrnd(av3.z, av3.w);
    *(u32x4*)&As[arow * 32 + acb] = p0;
    *(u32x4*)&As[arow * 32 + acb + 8] = p1;
    __syncthreads();  // A writes + B DMA visible (compiler drains cnts)

    bf16x8 af[4];
#pragma unroll
    for (int mt = 0; mt < 4; ++mt)
      af[mt] = *(const bf16x8*)&As[(wm + 16 * mt + lr) * 32 + 8 * quad];
#pragma unroll
    for (int nt = 0; nt < 4; ++nt) {
      bf16x8 bf = *(const bf16x8*)&Bs[(wn + 16 * nt + lr) * 32 + 8 * quad];
#pragma unroll
      for (int mt = 0; mt < 4; ++mt)
        acc[mt][nt] = __builtin_amdgcn_mfma_f32_16x16x32_bf16(af[mt], bf,
                                                              acc[mt][nt], 0, 0, 0);
    }
  }

  __syncthreads();  // As/Bs dead; Ts region now safe to write

  const int b_ = m0 >> 11;           // batch (128-row tile never crosses b)
  const int hbase = n0 >> 6;         // first head of this tile
  const int sgbase = (m0 & 2047) >> 5;  // first 32-row s-block

  if (mode < 2) {
    // Ts[s_local][d_local], stride 136
    const float osc = (mode == 0) ? 0.18033688011f : 1.0f;  // 0.125*log2(e)
#pragma unroll
    for (int mt = 0; mt < 4; ++mt)
#pragma unroll
      for (int nt = 0; nt < 4; ++nt) {
        int n = wn + 16 * nt + lr;
        int mb = wm + 16 * mt + 4 * quad;
#pragma unroll
        for (int r = 0; r < 4; ++r)
          Ts[(mb + r) * 136 + n] = f2b(acc[mt][nt][r] * osc);
      }
    __syncthreads();
    unsigned short* O = (mode == 0) ? QF : KF;
    const int ks = tid >> 6, lane2 = tid & 63;
    const int mrow = lane2 & 31, hb = lane2 >> 5;
#pragma unroll
    for (int c = 0; c < 8; ++c) {
      int hl = c >> 2, sblk = c & 3;
      int bh = b_ * HH + hbase + hl;
      bf16x8 vv = *(const bf16x8*)&Ts[(sblk * 32 + mrow) * 136 + hl * 64 +
                                      ks * 16 + hb * 8];
      *(bf16x8*)(O + ((size_t)bh * 64 + sgbase + sblk) * 2048 + tid * 8) = vv;
    }
  } else {
    // Ts[d_local][s_local], stride 136 (b64 writes: 4 consecutive s)
#pragma unroll
    for (int mt = 0; mt < 4; ++mt)
#pragma unroll
      for (int nt = 0; nt < 4; ++nt) {
        int n = wn + 16 * nt + lr;
        int mb = wm + 16 * mt + 4 * quad;
        *(us4*)&Ts[n * 136 + mb] =
            f2b4(acc[mt][nt][0], acc[mt][nt][1], acc[mt][nt][2], acc[mt][nt][3]);
      }
    __syncthreads();
    const int ntv = tid >> 7, ks2 = (tid >> 6) & 1, lane2 = tid & 63;
#pragma unroll
    for (int c = 0; c < 8; ++c) {
      int hl = c >> 2, sblk = c & 3;
      int bh = b_ * HH + hbase + hl;
      bf16x8 vv = *(const bf16x8*)&Ts[(hl * 64 + ntv * 32 + (lane2 & 31)) * 136 +
                                      sblk * 32 + ks2 * 16 + (lane2 >> 5) * 8];
      *(bf16x8*)(VF + ((size_t)bh * 64 + sgbase + sblk) * 2048 + tid * 8) = vv;
    }
  }
}

// ---------------------------------------------------------------------------
// Flash attention — r4 version restored verbatim (best measured: 79.3 us).
// 32x32x16 MFMA, barrier-free main loop, fragment-major global loads,
// software-pipelined tile pairs, P in registers (cvt_pk + permlane32_swap),
// no-max softmax (scale pre-folded into Q), XCD swizzle (6 bh per XCD).
// ---------------------------------------------------------------------------
struct KV {
  bf16x8 k[4];
  bf16x8 v[4];
};

__global__ __launch_bounds__(256) void attn(
    const unsigned short* __restrict__ QF, const unsigned short* __restrict__ KF,
    const unsigned short* __restrict__ VF, unsigned short* __restrict__ cc) {
  // LDS: Osh (epilogue only) + Ls/Linv
  __shared__ __align__(16) char smem[19200];
  float (*Osh)[64][36] = (float (*)[64][36])smem;                    // 18432 B
  float (*Ls)[2][32] = (float (*)[2][32])(smem + 18432);             // 512 B
  float (*Linv)[32] = (float (*)[32])(smem + 18944);                 // 256 B

  const int tid = threadIdx.x;
  const int lane = tid & 63, w_ = tid >> 6;
  const int wq = w_ & 1, wk = w_ >> 1;
  const int m32 = lane & 31, h = lane >> 5;
  // bijective XCD swizzle (1536 blocks, 1536%8==0): XCD k owns bh 6k..6k+5
  const int lin = blockIdx.y * 32 + blockIdx.x;
  const int nlin = (lin & 7) * 192 + (lin >> 3);
  const int bh = nlin >> 5;
  const int q0 = (nlin & 31) * 64;
  const size_t perbh = (size_t)SS * DEPTH;

  const unsigned short* qfb = QF + (size_t)bh * perbh;
  const unsigned short* kfb = KF + (size_t)bh * perbh + (size_t)wk * 2048 + lane * 8;
  const unsigned short* vfb = VF + (size_t)bh * perbh + (size_t)wk * 2048 + lane * 8;

  bf16x8 qf[4];
  {
    const unsigned short* p = qfb + (size_t)((q0 >> 5) + wq) * 2048 + lane * 8;
#pragma unroll
    for (int ks = 0; ks < 4; ++ks) qf[ks] = *(const bf16x8*)(p + ks * 512);
  }

  f32x16 o[2];
#pragma unroll
  for (int nt = 0; nt < 2; ++nt)
#pragma unroll
    for (int r = 0; r < 16; ++r) o[nt][r] = 0.f;
  float l_lane = 0.f;

#define LOADKV(tile, dst)                                                    \
  do {                                                                       \
    const unsigned short* kp_ = kfb + (size_t)(tile) * 4096;                 \
    const unsigned short* vp_ = vfb + (size_t)(tile) * 4096;                 \
    _Pragma("unroll") for (int x_ = 0; x_ < 4; ++x_) {                       \
      (dst).k[x_] = *(const bf16x8*)(kp_ + x_ * 512);                        \
      (dst).v[x_] = *(const bf16x8*)(vp_ + x_ * 512);                        \
    }                                                                        \
  } while (0)

  // QK^T for one tile: st[4g+i] = S^T[key = i+8g+4h][q = m32]
#define QKCOMP(kv, st)                                                       \
  do {                                                                       \
    _Pragma("unroll") for (int r_ = 0; r_ < 16; ++r_) (st)[r_] = 0.f;        \
    __builtin_amdgcn_s_setprio(1);                                           \
    _Pragma("unroll") for (int ks_ = 0; ks_ < 4; ++ks_)                      \
        (st) = __builtin_amdgcn_mfma_f32_32x32x16_bf16((kv).k[ks_], qf[ks_], \
                                                       (st), 0, 0, 0);       \
    __builtin_amdgcn_s_setprio(0);                                           \
  } while (0)

  // exp2 + pack to bf16 PV A-fragments (cvt_pk + permlane32_swap), then PV.
  // pa[ks2][j] = P[q=m32][key = 16*ks2 + 8*h + j].
#define EXPPV(st, kv)                                                        \
  do {                                                                       \
    float e_[16];                                                            \
    _Pragma("unroll") for (int r_ = 0; r_ < 16; ++r_) e_[r_] = fexp2((st)[r_]); \
    _Pragma("unroll") for (int g_ = 0; g_ < 4; ++g_)                         \
        l_lane += (e_[4 * g_ + 0] + e_[4 * g_ + 1]) +                        \
                  (e_[4 * g_ + 2] + e_[4 * g_ + 3]);                         \
    unsigned w00 = cvtpk(e_[0], e_[1]), w01 = cvtpk(e_[2], e_[3]);           \
    unsigned w10 = cvtpk(e_[4], e_[5]), w11 = cvtpk(e_[6], e_[7]);           \
    unsigned w20 = cvtpk(e_[8], e_[9]), w21 = cvtpk(e_[10], e_[11]);         \
    unsigned w30 = cvtpk(e_[12], e_[13]), w31 = cvtpk(e_[14], e_[15]);       \
    u32x2 r0 = permswap(w00, w10);                                           \
    u32x2 r1 = permswap(w01, w11);                                           \
    u32x2 r2 = permswap(w20, w30);                                           \
    u32x2 r3 = permswap(w21, w31);                                           \
    u32x4 paw0, paw1;                                                        \
    paw0.x = r0.x; paw0.y = r1.x; paw0.z = r0.y; paw0.w = r1.y;              \
    paw1.x = r2.x; paw1.y = r3.x; paw1.z = r2.y; paw1.w = r3.y;              \
    bf16x8 pa0 = __builtin_bit_cast(bf16x8, paw0);                           \
    bf16x8 pa1 = __builtin_bit_cast(bf16x8, paw1);                           \
    __builtin_amdgcn_s_setprio(1);                                           \
    o[0] = __builtin_amdgcn_mfma_f32_32x32x16_bf16(pa0, (kv).v[0], o[0],     \
                                                   0, 0, 0);                 \
    o[1] = __builtin_amdgcn_mfma_f32_32x32x16_bf16(pa0, (kv).v[2], o[1],     \
                                                   0, 0, 0);                 \
    o[0] = __builtin_amdgcn_mfma_f32_32x32x16_bf16(pa1, (kv).v[1], o[0],     \
                                                   0, 0, 0);                 \
    o[1] = __builtin_amdgcn_mfma_f32_32x32x16_bf16(pa1, (kv).v[3], o[1],     \
                                                   0, 0, 0);                 \
    __builtin_amdgcn_s_setprio(0);                                           \
  } while (0)

  KV b0, b1;
  f32x16 st0, st1;
  LOADKV(0, b0);
  LOADKV(1, b1);
  for (int t = 0; t < 32; t += 2) {
    QKCOMP(b0, st0);
    QKCOMP(b1, st1);          // independent MFMAs fill the pipe...
    EXPPV(st0, b0);           // ...while b0's exp/pack runs on the VALU
    if (t + 2 < 32) LOADKV(t + 2, b0);  // b0 fully consumed
    EXPPV(st1, b1);           // covers PV(b0) MFMA latency
    if (t + 3 < 32) LOADKV(t + 3, b1);
  }

  // ---- epilogue: combine key-halves, normalize, store ----
  l_lane += __shfl_xor(l_lane, 32);
  if (h == 0) Ls[wq][wk][m32] = l_lane;
  __syncthreads();  // all waves out of main loop
  if (wk == 1) {
#pragma unroll
    for (int nt = 0; nt < 2; ++nt)
#pragma unroll
      for (int g = 0; g < 4; ++g) {
        float4 t = make_float4(o[nt][4 * g], o[nt][4 * g + 1], o[nt][4 * g + 2],
                               o[nt][4 * g + 3]);
        *(float4*)&Osh[wq][32 * nt + m32][8 * g + 4 * h] = t;
      }
  } else if (tid < 64) {
    int qq = tid & 31, ww = tid >> 5;
    Linv[ww][qq] = 1.f / (Ls[ww][0][qq] + Ls[ww][1][qq]);
  }
  __syncthreads();
  if (wk == 0) {
    const int b_ = bh / HH, h_ = bh % HH;
#pragma unroll
    for (int g = 0; g < 4; ++g) {
      float4 li = *(const float4*)&Linv[wq][8 * g + 4 * h];
      float lia[4] = {li.x, li.y, li.z, li.w};
#pragma unroll
      for (int nt = 0; nt < 2; ++nt) {
        float4 ot = *(const float4*)&Osh[wq][32 * nt + m32][8 * g + 4 * h];
        float oa[4] = {ot.x, ot.y, ot.z, ot.w};
#pragma unroll
        for (int r = 0; r < 4; ++r) {
          int qg = q0 + 32 * wq + 8 * g + 4 * h + r;
          float val = (o[nt][4 * g + r] + oa[r]) * lia[r];
          cc[((size_t)b_ * SS + qg) * DD + h_ * DEPTH + 32 * nt + m32] = f2b(val);
        }
      }
    }
  }
}

// ---------------------------------------------------------------------------
// Output projection: out = cc @ wo.T + bo (fp32 out).
// Same XCD swizzle as proj_qkv (384 blocks, 384%8==0).
// ---------------------------------------------------------------------------
__global__ __launch_bounds__(256) void proj_out(
    const unsigned short* __restrict__ cc, const unsigned short* __restrict__ wob,
    const float* __restrict__ bo, float* __restrict__ out) {
  __shared__ __align__(16) unsigned short As[128 * 32];
  __shared__ __align__(16) unsigned short Bs[128 * 32];

  const int tid = threadIdx.x;
  const int lane = tid & 63, w_ = tid >> 6;
  const int lr = lane & 15, quad = lane >> 4;
  const int wm = (w_ & 1) * 64, wn = (w_ >> 1) * 64;
  const int lin = blockIdx.y * 64 + blockIdx.x;
  const int nlin = (lin & 7) * 48 + (lin >> 3);
  const int m0 = (nlin / 6) * 128, n0 = (nlin % 6) * 128;
  const int grow = lane >> 2, gcol = (lane & 3) * 8;

  f32x4 acc[4][4];
#pragma unroll
  for (int mt = 0; mt < 4; ++mt)
#pragma unroll
    for (int nt = 0; nt < 4; ++nt) acc[mt][nt] = (f32x4){0.f, 0.f, 0.f, 0.f};

  for (int k0 = 0; k0 < DD; k0 += 32) {
    __syncthreads();
#pragma unroll
    for (int i = 0; i < 2; ++i) {
      int c = 4 * i + w_;
      int row = c * 16 + grow;
      gl16(cc + (size_t)(m0 + row) * DD + k0 + gcol, (char*)As + c * 1024);
      gl16(wob + (size_t)(n0 + row) * DD + k0 + gcol, (char*)Bs + c * 1024);
    }
    __syncthreads();

    bf16x8 af[4];
#pragma unroll
    for (int mt = 0; mt < 4; ++mt)
      af[mt] = *(const bf16x8*)&As[(wm + 16 * mt + lr) * 32 + 8 * quad];
#pragma unroll
    for (int nt = 0; nt < 4; ++nt) {
      bf16x8 bf = *(const bf16x8*)&Bs[(wn + 16 * nt + lr) * 32 + 8 * quad];
#pragma unroll
      for (int mt = 0; mt < 4; ++mt)
        acc[mt][nt] = __builtin_amdgcn_mfma_f32_16x16x32_bf16(af[mt], bf,
                                                              acc[mt][nt], 0, 0, 0);
    }
  }

#pragma unroll
  for (int mt = 0; mt < 4; ++mt)
#pragma unroll
    for (int nt = 0; nt < 4; ++nt) {
      int n = n0 + wn + 16 * nt + lr;
      float bias = bo[n];
#pragma unroll
      for (int r = 0; r < 4; ++r) {
        int m = m0 + wm + 16 * mt + 4 * quad + r;
        out[(size_t)m * DD + n] = acc[mt][nt][r] + bias;
      }
    }
}

extern "C" void kernel_launch(void* const* d_in, const int* in_sizes, int n_in,
                              void* d_out, int out_size, void* d_ws,
                              size_t ws_size, hipStream_t stream) {
  const float* v = (const float*)d_in[0];
  const float* k = (const float*)d_in[1];
  const float* q = (const float*)d_in[2];
  const float* wq = (const float*)d_in[3];
  const float* wk = (const float*)d_in[4];
  const float* wv = (const float*)d_in[5];
  const float* wo = (const float*)d_in[6];
  const float* bo = (const float*)d_in[7];
  float* out = (float*)d_out;

  const size_t per = (size_t)BB * HH * SS * DEPTH;  // 6291456
  unsigned short* QF = (unsigned short*)d_ws;
  unsigned short* KF = QF + per;
  unsigned short* VF = KF + per;
  unsigned short* cc = VF + per;
  unsigned short* wqb = cc + per;
  unsigned short* wkb = wqb + WSZ;
  unsigned short* wvb = wkb + WSZ;
  unsigned short* wob = wvb + WSZ;

  // weights only: 4 x 576 blocks
  prep<<<dim3(2304), 256, 0, stream>>>(wq, wk, wv, wo, wqb, wkb, wvb, wob);

  dim3 g1(M_TOTAL / 128, DD / 128, 3);
  proj_qkv<<<g1, 256, 0, stream>>>(q, k, v, wqb, wkb, wvb, QF, KF, VF);

  dim3 g2(SS / 64, BB * HH);
  attn<<<g2, 256, 0, stream>>>(QF, KF, VF, cc);

  dim3 g3(M_TOTAL / 128, DD / 128);
  proj_out<<<g3, 256, 0, stream>>>(cc, wob, bo, out);
}

// Round 8
// 273.611 us; speedup vs baseline: 1.0710x; 1.0710x over previous
//
#include <hip/hip_runtime.h>
#include <math.h>

#define BB 4
#define SS 2048
#define DD 768
#define HH 12
#define DEPTH 64
#define M_TOTAL (BB * SS)  // 8192
#define WSZ (DD * DD)      // 589824

typedef __attribute__((ext_vector_type(8))) short bf16x8;
typedef __attribute__((ext_vector_type(16))) float f32x16;
typedef __attribute__((ext_vector_type(4))) float f32x4;
typedef __attribute__((ext_vector_type(4))) unsigned short us4;
typedef __attribute__((ext_vector_type(2))) unsigned int u32x2;
typedef __attribute__((ext_vector_type(4))) unsigned int u32x4;

// fp32 -> bf16, round-half-up (2 ops); inputs are finite
__device__ __forceinline__ unsigned short f2b(float f) {
  unsigned u = __builtin_bit_cast(unsigned, f);
  return (unsigned short)((u + 0x8000u) >> 16);
}

// pack two fp32 -> bf16x2 (lo, hi) via v_perm_b32: 3 VALU total
__device__ __forceinline__ unsigned pkrnd(float lo, float hi) {
  unsigned a = __builtin_bit_cast(unsigned, lo) + 0x8000u;
  unsigned b = __builtin_bit_cast(unsigned, hi) + 0x8000u;
  return __builtin_amdgcn_perm(b, a, 0x07060302);  // {b.hi16, a.hi16}
}

__device__ __forceinline__ us4 f2b4(float a, float b, float c, float d) {
  unsigned lo = pkrnd(a, b), hi = pkrnd(c, d);
  us4 t;
  t.x = (unsigned short)lo; t.y = (unsigned short)(lo >> 16);
  t.z = (unsigned short)hi; t.w = (unsigned short)(hi >> 16);
  return t;
}

// single-instruction pack: {lo16: bf16(a), hi16: bf16(b)}
__device__ __forceinline__ unsigned cvtpk(float a, float b) {
  unsigned d;
  asm("v_cvt_pk_bf16_f32 %0, %1, %2" : "=v"(d) : "v"(a), "v"(b));
  return d;
}

// v_permlane32_swap_b32: returns {a.lo|b.lo, a.hi|b.hi}
__device__ __forceinline__ u32x2 permswap(unsigned a, unsigned b) {
  auto r = __builtin_amdgcn_permlane32_swap(a, b, false, false);
  u32x2 out;
  out.x = r[0];
  out.y = r[1];
  return out;
}

__device__ __forceinline__ float fexp2(float x) {
  return __builtin_amdgcn_exp2f(x);
}

// async global->LDS, 16B per lane; lds dest = wave-uniform base + lane*16
__device__ __forceinline__ void gl16(const void* g, void* l) {
  __builtin_amdgcn_global_load_lds(
      (const __attribute__((address_space(1))) unsigned int*)g,
      (__attribute__((address_space(3))) unsigned int*)l, 16, 0, 0);
}

// ---------------------------------------------------------------------------
// Prep: fp32 -> bf16 for the 3 activations and 4 weights.
// Exact-sized flat grid (20736 blocks): 3x6144 activation blocks, 4x576
// weight blocks — no no-op blocks.
// ---------------------------------------------------------------------------
__global__ __launch_bounds__(256) void prep(
    const float* __restrict__ s0, const float* __restrict__ s1,
    const float* __restrict__ s2, const float* __restrict__ s3,
    const float* __restrict__ s4, const float* __restrict__ s5,
    const float* __restrict__ s6, unsigned short* __restrict__ d0,
    unsigned short* __restrict__ d1, unsigned short* __restrict__ d2,
    unsigned short* __restrict__ d3, unsigned short* __restrict__ d4,
    unsigned short* __restrict__ d5, unsigned short* __restrict__ d6) {
  const float* s;
  unsigned short* d;
  int b = blockIdx.x, lb;
  if (b < 18432) {
    int mode = b / 6144;
    lb = b - mode * 6144;
    if (mode == 0) { s = s0; d = d0; }
    else if (mode == 1) { s = s1; d = d1; }
    else { s = s2; d = d2; }
  } else {
    int t = b - 18432;
    int mode = t / 576;
    lb = t - mode * 576;
    if (mode == 0) { s = s3; d = d3; }
    else if (mode == 1) { s = s4; d = d4; }
    else if (mode == 2) { s = s5; d = d5; }
    else { s = s6; d = d6; }
  }
  int idx = (lb * 256 + threadIdx.x) * 4;
  float4 f = *(const float4*)(s + idx);
  *(us4*)(d + idx) = f2b4(f.x, f.y, f.z, f.w);
}

// ---------------------------------------------------------------------------
// QKV projection (bf16 in, global_load_lds staging, 128x128 tile, BK=64).
// BK=64 halves the K-loop iteration count (24->12) and therefore the number
// of barrier vmcnt/lgkm drains (the m97-structure's known ~20% stall) while
// LDS stays under the Ts-union footprint (As/Bs 16KB each).
// Fragment-major outputs (QF/KF/VF), epilogue through LDS transpose tile:
//   QF/KF[bh][sblk(64)][ks(4)][lane2(64)][j(8)]
//   VF[bh][sblk(64)][ntv(2)][ks2(2)][lane2(64)][j(8)]
// Q scaled by 0.125*log2(e) (softmax scale folded, exp2 base).
// XCD-aware bijective swizzle (384 blocks per z).
// ---------------------------------------------------------------------------
__global__ __launch_bounds__(256) void proj_qkv(
    const unsigned short* __restrict__ qb, const unsigned short* __restrict__ kb,
    const unsigned short* __restrict__ vb, const unsigned short* __restrict__ wqb,
    const unsigned short* __restrict__ wkb, const unsigned short* __restrict__ wvb,
    unsigned short* __restrict__ QF, unsigned short* __restrict__ KF,
    unsigned short* __restrict__ VF) {
  const int mode = blockIdx.z;
  const unsigned short* X;
  const unsigned short* W;
  if (mode == 0) { X = qb; W = wqb; }
  else if (mode == 1) { X = kb; W = wkb; }
  else { X = vb; W = wvb; }

  // union: As/Bs (32 KB, BK=64) live during K-loop; Ts (34816 B) in epilogue
  __shared__ __align__(16) char sm[34816];
  unsigned short* As = (unsigned short*)sm;            // [128][64]
  unsigned short* Bs = (unsigned short*)(sm + 16384);  // [128][64]
  unsigned short* Ts = (unsigned short*)sm;            // [128][136]

  const int tid = threadIdx.x;
  const int lane = tid & 63, w_ = tid >> 6;
  const int lr = lane & 15, quad = lane >> 4;
  const int wm = (w_ & 1) * 64, wn = (w_ >> 1) * 64;
  // bijective XCD swizzle (384 blocks per z, 384%8==0)
  const int lin = blockIdx.y * 64 + blockIdx.x;
  const int nlin = (lin & 7) * 48 + (lin >> 3);
  const int m0 = (nlin / 6) * 128, n0 = (nlin % 6) * 128;
  // staging coords: chunk c (1KB = 8 rows x 128B); lane covers 16B
  const int srow = lane >> 3, scol = (lane & 7) * 8;

  f32x4 acc[4][4];
#pragma unroll
  for (int mt = 0; mt < 4; ++mt)
#pragma unroll
    for (int nt = 0; nt < 4; ++nt) acc[mt][nt] = (f32x4){0.f, 0.f, 0.f, 0.f};

  for (int k0 = 0; k0 < DD; k0 += 64) {
    __syncthreads();
#pragma unroll
    for (int i = 0; i < 4; ++i) {
      int c = 4 * i + w_;          // 16 chunks per matrix
      int row = c * 8 + srow;
      gl16(X + (size_t)(m0 + row) * DD + k0 + scol, (char*)As + c * 1024);
      gl16(W + (size_t)(n0 + row) * DD + k0 + scol, (char*)Bs + c * 1024);
    }
    __syncthreads();

#pragma unroll
    for (int s = 0; s < 2; ++s) {
      bf16x8 af[4];
#pragma unroll
      for (int mt = 0; mt < 4; ++mt)
        af[mt] = *(const bf16x8*)&As[(wm + 16 * mt + lr) * 64 + 32 * s + 8 * quad];
#pragma unroll
      for (int nt = 0; nt < 4; ++nt) {
        bf16x8 bf = *(const bf16x8*)&Bs[(wn + 16 * nt + lr) * 64 + 32 * s + 8 * quad];
#pragma unroll
        for (int mt = 0; mt < 4; ++mt)
          acc[mt][nt] = __builtin_amdgcn_mfma_f32_16x16x32_bf16(af[mt], bf,
                                                                acc[mt][nt], 0, 0, 0);
      }
    }
  }

  __syncthreads();  // As/Bs dead; Ts region now safe to write

  const int b_ = m0 >> 11;           // batch (128-row tile never crosses b)
  const int hbase = n0 >> 6;         // first head of this tile
  const int sgbase = (m0 & 2047) >> 5;  // first 32-row s-block

  if (mode < 2) {
    // Ts[s_local][d_local], stride 136
    const float osc = (mode == 0) ? 0.18033688011f : 1.0f;  // 0.125*log2(e)
#pragma unroll
    for (int mt = 0; mt < 4; ++mt)
#pragma unroll
      for (int nt = 0; nt < 4; ++nt) {
        int n = wn + 16 * nt + lr;
        int mb = wm + 16 * mt + 4 * quad;
#pragma unroll
        for (int r = 0; r < 4; ++r)
          Ts[(mb + r) * 136 + n] = f2b(acc[mt][nt][r] * osc);
      }
    __syncthreads();
    unsigned short* O = (mode == 0) ? QF : KF;
    const int ks = tid >> 6, lane2 = tid & 63;
    const int mrow = lane2 & 31, hb = lane2 >> 5;
#pragma unroll
    for (int c = 0; c < 8; ++c) {
      int hl = c >> 2, sblk = c & 3;
      int bh = b_ * HH + hbase + hl;
      bf16x8 vv = *(const bf16x8*)&Ts[(sblk * 32 + mrow) * 136 + hl * 64 +
                                      ks * 16 + hb * 8];
      *(bf16x8*)(O + ((size_t)bh * 64 + sgbase + sblk) * 2048 + tid * 8) = vv;
    }
  } else {
    // Ts[d_local][s_local], stride 136 (b64 writes: 4 consecutive s)
#pragma unroll
    for (int mt = 0; mt < 4; ++mt)
#pragma unroll
      for (int nt = 0; nt < 4; ++nt) {
        int n = wn + 16 * nt + lr;
        int mb = wm + 16 * mt + 4 * quad;
        *(us4*)&Ts[n * 136 + mb] =
            f2b4(acc[mt][nt][0], acc[mt][nt][1], acc[mt][nt][2], acc[mt][nt][3]);
      }
    __syncthreads();
    const int ntv = tid >> 7, ks2 = (tid >> 6) & 1, lane2 = tid & 63;
#pragma unroll
    for (int c = 0; c < 8; ++c) {
      int hl = c >> 2, sblk = c & 3;
      int bh = b_ * HH + hbase + hl;
      bf16x8 vv = *(const bf16x8*)&Ts[(hl * 64 + ntv * 32 + (lane2 & 31)) * 136 +
                                      sblk * 32 + ks2 * 16 + (lane2 >> 5) * 8];
      *(bf16x8*)(VF + ((size_t)bh * 64 + sgbase + sblk) * 2048 + tid * 8) = vv;
    }
  }
}

// ---------------------------------------------------------------------------
// Flash attention — r4 version verbatim (best measured: 79.3 us).
// 32x32x16 MFMA, barrier-free main loop, fragment-major global loads,
// software-pipelined tile pairs, P in registers (cvt_pk + permlane32_swap),
// no-max softmax (scale pre-folded into Q), XCD swizzle (6 bh per XCD).
// ---------------------------------------------------------------------------
struct KV {
  bf16x8 k[4];
  bf16x8 v[4];
};

__global__ __launch_bounds__(256) void attn(
    const unsigned short* __restrict__ QF, const unsigned short* __restrict__ KF,
    const unsigned short* __restrict__ VF, unsigned short* __restrict__ cc) {
  // LDS: Osh (epilogue only) + Ls/Linv
  __shared__ __align__(16) char smem[19200];
  float (*Osh)[64][36] = (float (*)[64][36])smem;                    // 18432 B
  float (*Ls)[2][32] = (float (*)[2][32])(smem + 18432);             // 512 B
  float (*Linv)[32] = (float (*)[32])(smem + 18944);                 // 256 B

  const int tid = threadIdx.x;
  const int lane = tid & 63, w_ = tid >> 6;
  const int wq = w_ & 1, wk = w_ >> 1;
  const int m32 = lane & 31, h = lane >> 5;
  // bijective XCD swizzle (1536 blocks, 1536%8==0): XCD k owns bh 6k..6k+5
  const int lin = blockIdx.y * 32 + blockIdx.x;
  const int nlin = (lin & 7) * 192 + (lin >> 3);
  const int bh = nlin >> 5;
  const int q0 = (nlin & 31) * 64;
  const size_t perbh = (size_t)SS * DEPTH;

  const unsigned short* qfb = QF + (size_t)bh * perbh;
  const unsigned short* kfb = KF + (size_t)bh * perbh + (size_t)wk * 2048 + lane * 8;
  const unsigned short* vfb = VF + (size_t)bh * perbh + (size_t)wk * 2048 + lane * 8;

  bf16x8 qf[4];
  {
    const unsigned short* p = qfb + (size_t)((q0 >> 5) + wq) * 2048 + lane * 8;
#pragma unroll
    for (int ks = 0; ks < 4; ++ks) qf[ks] = *(const bf16x8*)(p + ks * 512);
  }

  f32x16 o[2];
#pragma unroll
  for (int nt = 0; nt < 2; ++nt)
#pragma unroll
    for (int r = 0; r < 16; ++r) o[nt][r] = 0.f;
  float l_lane = 0.f;

#define LOADKV(tile, dst)                                                    \
  do {                                                                       \
    const unsigned short* kp_ = kfb + (size_t)(tile) * 4096;                 \
    const unsigned short* vp_ = vfb + (size_t)(tile) * 4096;                 \
    _Pragma("unroll") for (int x_ = 0; x_ < 4; ++x_) {                       \
      (dst).k[x_] = *(const bf16x8*)(kp_ + x_ * 512);                        \
      (dst).v[x_] = *(const bf16x8*)(vp_ + x_ * 512);                        \
    }                                                                        \
  } while (0)

  // QK^T for one tile: st[4g+i] = S^T[key = i+8g+4h][q = m32]
#define QKCOMP(kv, st)                                                       \
  do {                                                                       \
    _Pragma("unroll") for (int r_ = 0; r_ < 16; ++r_) (st)[r_] = 0.f;        \
    __builtin_amdgcn_s_setprio(1);                                           \
    _Pragma("unroll") for (int ks_ = 0; ks_ < 4; ++ks_)                      \
        (st) = __builtin_amdgcn_mfma_f32_32x32x16_bf16((kv).k[ks_], qf[ks_], \
                                                       (st), 0, 0, 0);       \
    __builtin_amdgcn_s_setprio(0);                                           \
  } while (0)

  // exp2 + pack to bf16 PV A-fragments (cvt_pk + permlane32_swap), then PV.
  // pa[ks2][j] = P[q=m32][key = 16*ks2 + 8*h + j].
#define EXPPV(st, kv)                                                        \
  do {                                                                       \
    float e_[16];                                                            \
    _Pragma("unroll") for (int r_ = 0; r_ < 16; ++r_) e_[r_] = fexp2((st)[r_]); \
    _Pragma("unroll") for (int g_ = 0; g_ < 4; ++g_)                         \
        l_lane += (e_[4 * g_ + 0] + e_[4 * g_ + 1]) +                        \
                  (e_[4 * g_ + 2] + e_[4 * g_ + 3]);                         \
    unsigned w00 = cvtpk(e_[0], e_[1]), w01 = cvtpk(e_[2], e_[3]);           \
    unsigned w10 = cvtpk(e_[4], e_[5]), w11 = cvtpk(e_[6], e_[7]);           \
    unsigned w20 = cvtpk(e_[8], e_[9]), w21 = cvtpk(e_[10], e_[11]);         \
    unsigned w30 = cvtpk(e_[12], e_[13]), w31 = cvtpk(e_[14], e_[15]);       \
    u32x2 r0 = permswap(w00, w10);                                           \
    u32x2 r1 = permswap(w01, w11);                                           \
    u32x2 r2 = permswap(w20, w30);                                           \
    u32x2 r3 = permswap(w21, w31);                                           \
    u32x4 paw0, paw1;                                                        \
    paw0.x = r0.x; paw0.y = r1.x; paw0.z = r0.y; paw0.w = r1.y;              \
    paw1.x = r2.x; paw1.y = r3.x; paw1.z = r2.y; paw1.w = r3.y;              \
    bf16x8 pa0 = __builtin_bit_cast(bf16x8, paw0);                           \
    bf16x8 pa1 = __builtin_bit_cast(bf16x8, paw1);                           \
    __builtin_amdgcn_s_setprio(1);                                           \
    o[0] = __builtin_amdgcn_mfma_f32_32x32x16_bf16(pa0, (kv).v[0], o[0],     \
                                                   0, 0, 0);                 \
    o[1] = __builtin_amdgcn_mfma_f32_32x32x16_bf16(pa0, (kv).v[2], o[1],     \
                                                   0, 0, 0);                 \
    o[0] = __builtin_amdgcn_mfma_f32_32x32x16_bf16(pa1, (kv).v[1], o[0],     \
                                                   0, 0, 0);                 \
    o[1] = __builtin_amdgcn_mfma_f32_32x32x16_bf16(pa1, (kv).v[3], o[1],     \
                                                   0, 0, 0);                 \
    __builtin_amdgcn_s_setprio(0);                                           \
  } while (0)

  KV b0, b1;
  f32x16 st0, st1;
  LOADKV(0, b0);
  LOADKV(1, b1);
  for (int t = 0; t < 32; t += 2) {
    QKCOMP(b0, st0);
    QKCOMP(b1, st1);          // independent MFMAs fill the pipe...
    EXPPV(st0, b0);           // ...while b0's exp/pack runs on the VALU
    if (t + 2 < 32) LOADKV(t + 2, b0);  // b0 fully consumed
    EXPPV(st1, b1);           // covers PV(b0) MFMA latency
    if (t + 3 < 32) LOADKV(t + 3, b1);
  }

  // ---- epilogue: combine key-halves, normalize, store ----
  l_lane += __shfl_xor(l_lane, 32);
  if (h == 0) Ls[wq][wk][m32] = l_lane;
  __syncthreads();  // all waves out of main loop
  if (wk == 1) {
#pragma unroll
    for (int nt = 0; nt < 2; ++nt)
#pragma unroll
      for (int g = 0; g < 4; ++g) {
        float4 t = make_float4(o[nt][4 * g], o[nt][4 * g + 1], o[nt][4 * g + 2],
                               o[nt][4 * g + 3]);
        *(float4*)&Osh[wq][32 * nt + m32][8 * g + 4 * h] = t;
      }
  } else if (tid < 64) {
    int qq = tid & 31, ww = tid >> 5;
    Linv[ww][qq] = 1.f / (Ls[ww][0][qq] + Ls[ww][1][qq]);
  }
  __syncthreads();
  if (wk == 0) {
    const int b_ = bh / HH, h_ = bh % HH;
#pragma unroll
    for (int g = 0; g < 4; ++g) {
      float4 li = *(const float4*)&Linv[wq][8 * g + 4 * h];
      float lia[4] = {li.x, li.y, li.z, li.w};
#pragma unroll
      for (int nt = 0; nt < 2; ++nt) {
        float4 ot = *(const float4*)&Osh[wq][32 * nt + m32][8 * g + 4 * h];
        float oa[4] = {ot.x, ot.y, ot.z, ot.w};
#pragma unroll
        for (int r = 0; r < 4; ++r) {
          int qg = q0 + 32 * wq + 8 * g + 4 * h + r;
          float val = (o[nt][4 * g + r] + oa[r]) * lia[r];
          cc[((size_t)b_ * SS + qg) * DD + h_ * DEPTH + 32 * nt + m32] = f2b(val);
        }
      }
    }
  }
}

// ---------------------------------------------------------------------------
// Output projection: out = cc @ wo.T + bo (fp32 out), BK=64 (same rationale
// as proj_qkv). Same XCD swizzle (384 blocks, 384%8==0).
// ---------------------------------------------------------------------------
__global__ __launch_bounds__(256) void proj_out(
    const unsigned short* __restrict__ cc, const unsigned short* __restrict__ wob,
    const float* __restrict__ bo, float* __restrict__ out) {
  __shared__ __align__(16) unsigned short As[128 * 64];
  __shared__ __align__(16) unsigned short Bs[128 * 64];

  const int tid = threadIdx.x;
  const int lane = tid & 63, w_ = tid >> 6;
  const int lr = lane & 15, quad = lane >> 4;
  const int wm = (w_ & 1) * 64, wn = (w_ >> 1) * 64;
  const int lin = blockIdx.y * 64 + blockIdx.x;
  const int nlin = (lin & 7) * 48 + (lin >> 3);
  const int m0 = (nlin / 6) * 128, n0 = (nlin % 6) * 128;
  const int srow = lane >> 3, scol = (lane & 7) * 8;

  f32x4 acc[4][4];
#pragma unroll
  for (int mt = 0; mt < 4; ++mt)
#pragma unroll
    for (int nt = 0; nt < 4; ++nt) acc[mt][nt] = (f32x4){0.f, 0.f, 0.f, 0.f};

  for (int k0 = 0; k0 < DD; k0 += 64) {
    __syncthreads();
#pragma unroll
    for (int i = 0; i < 4; ++i) {
      int c = 4 * i + w_;
      int row = c * 8 + srow;
      gl16(cc + (size_t)(m0 + row) * DD + k0 + scol, (char*)As + c * 1024);
      gl16(wob + (size_t)(n0 + row) * DD + k0 + scol, (char*)Bs + c * 1024);
    }
    __syncthreads();

#pragma unroll
    for (int s = 0; s < 2; ++s) {
      bf16x8 af[4];
#pragma unroll
      for (int mt = 0; mt < 4; ++mt)
        af[mt] = *(const bf16x8*)&As[(wm + 16 * mt + lr) * 64 + 32 * s + 8 * quad];
#pragma unroll
      for (int nt = 0; nt < 4; ++nt) {
        bf16x8 bf = *(const bf16x8*)&Bs[(wn + 16 * nt + lr) * 64 + 32 * s + 8 * quad];
#pragma unroll
        for (int mt = 0; mt < 4; ++mt)
          acc[mt][nt] = __builtin_amdgcn_mfma_f32_16x16x32_bf16(af[mt], bf,
                                                                acc[mt][nt], 0, 0, 0);
      }
    }
  }

#pragma unroll
  for (int mt = 0; mt < 4; ++mt)
#pragma unroll
    for (int nt = 0; nt < 4; ++nt) {
      int n = n0 + wn + 16 * nt + lr;
      float bias = bo[n];
#pragma unroll
      for (int r = 0; r < 4; ++r) {
        int m = m0 + wm + 16 * mt + 4 * quad + r;
        out[(size_t)m * DD + n] = acc[mt][nt][r] + bias;
      }
    }
}

extern "C" void kernel_launch(void* const* d_in, const int* in_sizes, int n_in,
                              void* d_out, int out_size, void* d_ws,
                              size_t ws_size, hipStream_t stream) {
  const float* v = (const float*)d_in[0];
  const float* k = (const float*)d_in[1];
  const float* q = (const float*)d_in[2];
  const float* wq = (const float*)d_in[3];
  const float* wk = (const float*)d_in[4];
  const float* wv = (const float*)d_in[5];
  const float* wo = (const float*)d_in[6];
  const float* bo = (const float*)d_in[7];
  float* out = (float*)d_out;

  const size_t per = (size_t)BB * HH * SS * DEPTH;  // 6291456
  unsigned short* QF = (unsigned short*)d_ws;
  unsigned short* KF = QF + per;
  unsigned short* VF = KF + per;
  unsigned short* cc = VF + per;
  unsigned short* qb = cc + per;
  unsigned short* kb = qb + per;
  unsigned short* vb = kb + per;
  unsigned short* wqb = vb + per;
  unsigned short* wkb = wqb + WSZ;
  unsigned short* wvb = wkb + WSZ;
  unsigned short* wob = wvb + WSZ;

  // exact grid: 3*6144 activation blocks + 4*576 weight blocks
  prep<<<dim3(20736), 256, 0, stream>>>(q, k, v, wq, wk, wv, wo, qb, kb, vb,
                                        wqb, wkb, wvb, wob);

  dim3 g1(M_TOTAL / 128, DD / 128, 3);
  proj_qkv<<<g1, 256, 0, stream>>>(qb, kb, vb, wqb, wkb, wvb, QF, KF, VF);

  dim3 g2(SS / 64, BB * HH);
  attn<<<g2, 256, 0, stream>>>(QF, KF, VF, cc);

  dim3 g3(M_TOTAL / 128, DD / 128);
  proj_out<<<g3, 256, 0, stream>>>(cc, wob, bo, out);
}

// Round 9
// 264.088 us; speedup vs baseline: 1.1096x; 1.0361x over previous
//
#include <hip/hip_runtime.h>
#include <math.h>

#define BB 4
#define SS 2048
#define DD 768
#define HH 12
#define DEPTH 64
#define M_TOTAL (BB * SS)  // 8192
#define WSZ (DD * DD)      // 589824

typedef __attribute__((ext_vector_type(8))) short bf16x8;
typedef __attribute__((ext_vector_type(16))) float f32x16;
typedef __attribute__((ext_vector_type(4))) float f32x4;
typedef __attribute__((ext_vector_type(4))) unsigned short us4;
typedef __attribute__((ext_vector_type(2))) unsigned int u32x2;
typedef __attribute__((ext_vector_type(4))) unsigned int u32x4;

// fp32 -> bf16, round-half-up (2 ops); inputs are finite
__device__ __forceinline__ unsigned short f2b(float f) {
  unsigned u = __builtin_bit_cast(unsigned, f);
  return (unsigned short)((u + 0x8000u) >> 16);
}

// pack two fp32 -> bf16x2 (lo, hi) via v_perm_b32: 3 VALU total
__device__ __forceinline__ unsigned pkrnd(float lo, float hi) {
  unsigned a = __builtin_bit_cast(unsigned, lo) + 0x8000u;
  unsigned b = __builtin_bit_cast(unsigned, hi) + 0x8000u;
  return __builtin_amdgcn_perm(b, a, 0x07060302);  // {b.hi16, a.hi16}
}

__device__ __forceinline__ us4 f2b4(float a, float b, float c, float d) {
  unsigned lo = pkrnd(a, b), hi = pkrnd(c, d);
  us4 t;
  t.x = (unsigned short)lo; t.y = (unsigned short)(lo >> 16);
  t.z = (unsigned short)hi; t.w = (unsigned short)(hi >> 16);
  return t;
}

// single-instruction pack: {lo16: bf16(a), hi16: bf16(b)}
__device__ __forceinline__ unsigned cvtpk(float a, float b) {
  unsigned d;
  asm("v_cvt_pk_bf16_f32 %0, %1, %2" : "=v"(d) : "v"(a), "v"(b));
  return d;
}

// v_permlane32_swap_b32: returns {a.lo|b.lo, a.hi|b.hi}
__device__ __forceinline__ u32x2 permswap(unsigned a, unsigned b) {
  auto r = __builtin_amdgcn_permlane32_swap(a, b, false, false);
  u32x2 out;
  out.x = r[0];
  out.y = r[1];
  return out;
}

__device__ __forceinline__ float fexp2(float x) {
  return __builtin_amdgcn_exp2f(x);
}

// async global->LDS, 16B per lane; lds dest = wave-uniform base + lane*16
__device__ __forceinline__ void gl16(const void* g, void* l) {
  __builtin_amdgcn_global_load_lds(
      (const __attribute__((address_space(1))) unsigned int*)g,
      (__attribute__((address_space(3))) unsigned int*)l, 16, 0, 0);
}

// ---------------------------------------------------------------------------
// Prep: fp32 -> bf16 for the 3 activations and 4 weights.
// Exact-sized flat grid (20736 blocks): 3x6144 activation blocks, 4x576
// weight blocks — no no-op blocks.
// ---------------------------------------------------------------------------
__global__ __launch_bounds__(256) void prep(
    const float* __restrict__ s0, const float* __restrict__ s1,
    const float* __restrict__ s2, const float* __restrict__ s3,
    const float* __restrict__ s4, const float* __restrict__ s5,
    const float* __restrict__ s6, unsigned short* __restrict__ d0,
    unsigned short* __restrict__ d1, unsigned short* __restrict__ d2,
    unsigned short* __restrict__ d3, unsigned short* __restrict__ d4,
    unsigned short* __restrict__ d5, unsigned short* __restrict__ d6) {
  const float* s;
  unsigned short* d;
  int b = blockIdx.x, lb;
  if (b < 18432) {
    int mode = b / 6144;
    lb = b - mode * 6144;
    if (mode == 0) { s = s0; d = d0; }
    else if (mode == 1) { s = s1; d = d1; }
    else { s = s2; d = d2; }
  } else {
    int t = b - 18432;
    int mode = t / 576;
    lb = t - mode * 576;
    if (mode == 0) { s = s3; d = d3; }
    else if (mode == 1) { s = s4; d = d4; }
    else if (mode == 2) { s = s5; d = d5; }
    else { s = s6; d = d6; }
  }
  int idx = (lb * 256 + threadIdx.x) * 4;
  float4 f = *(const float4*)(s + idx);
  *(us4*)(d + idx) = f2b4(f.x, f.y, f.z, f.w);
}

// ---------------------------------------------------------------------------
// QKV projection (bf16 in, 128x128 tile, BK=32, DOUBLE-BUFFERED pipeline):
// per K-iteration: issue STAGE(t+1) into buf^1, ds_read+MFMA on buf, own
// vmcnt(0), one s_barrier (T3 minimum 2-phase — stage latency hides under
// compute instead of being serially drained as in the old 2-barrier form).
// LDS: 2 x (As 8KB + Bs 8KB) = 32 KB, still under the 34816 B Ts union ->
// occupancy unchanged. Fragment-major outputs, LDS-transpose epilogue:
//   QF/KF[bh][sblk(64)][ks(4)][lane2(64)][j(8)]
//   VF[bh][sblk(64)][ntv(2)][ks2(2)][lane2(64)][j(8)]
// Q scaled by 0.125*log2(e). XCD-aware bijective swizzle (384 blocks/z).
// ---------------------------------------------------------------------------
__global__ __launch_bounds__(256) void proj_qkv(
    const unsigned short* __restrict__ qb, const unsigned short* __restrict__ kb,
    const unsigned short* __restrict__ vb, const unsigned short* __restrict__ wqb,
    const unsigned short* __restrict__ wkb, const unsigned short* __restrict__ wvb,
    unsigned short* __restrict__ QF, unsigned short* __restrict__ KF,
    unsigned short* __restrict__ VF) {
  const int mode = blockIdx.z;
  const unsigned short* X;
  const unsigned short* W;
  if (mode == 0) { X = qb; W = wqb; }
  else if (mode == 1) { X = kb; W = wkb; }
  else { X = vb; W = wvb; }

  // union: dbuf As/Bs (32 KB) during K-loop; Ts (34816 B) in epilogue
  __shared__ __align__(16) char sm[34816];
  unsigned short* Ts = (unsigned short*)sm;  // [128][136]

  const int tid = threadIdx.x;
  const int lane = tid & 63, w_ = tid >> 6;
  const int lr = lane & 15, quad = lane >> 4;
  const int wm = (w_ & 1) * 64, wn = (w_ >> 1) * 64;
  // bijective XCD swizzle (384 blocks per z, 384%8==0)
  const int lin = blockIdx.y * 64 + blockIdx.x;
  const int nlin = (lin & 7) * 48 + (lin >> 3);
  const int m0 = (nlin / 6) * 128, n0 = (nlin % 6) * 128;
  const int grow = lane >> 2, gcol = (lane & 3) * 8;

  f32x4 acc[4][4];
#pragma unroll
  for (int mt = 0; mt < 4; ++mt)
#pragma unroll
    for (int nt = 0; nt < 4; ++nt) acc[mt][nt] = (f32x4){0.f, 0.f, 0.f, 0.f};

  // stage one BK=32 tile (A 8KB + B 8KB) into buffer at byte offset bufo
#define STAGEP(k0, bufo)                                                     \
  do {                                                                       \
    _Pragma("unroll") for (int i_ = 0; i_ < 2; ++i_) {                       \
      int c_ = 4 * i_ + w_;                                                  \
      int row_ = c_ * 16 + grow;                                             \
      gl16(X + (size_t)(m0 + row_) * DD + (k0) + gcol,                       \
           sm + (bufo) + c_ * 1024);                                         \
      gl16(W + (size_t)(n0 + row_) * DD + (k0) + gcol,                       \
           sm + (bufo) + 8192 + c_ * 1024);                                  \
    }                                                                        \
  } while (0)

  STAGEP(0, 0);
  asm volatile("s_waitcnt vmcnt(0)" ::: "memory");
  __builtin_amdgcn_s_barrier();
  __builtin_amdgcn_sched_barrier(0);

  for (int k = 0; k < 24; ++k) {
    const int cur = (k & 1) << 14;  // 0 / 16384
    if (k + 1 < 24) STAGEP((k + 1) * 32, cur ^ 16384);
    const unsigned short* As = (const unsigned short*)(sm + cur);
    const unsigned short* Bs = (const unsigned short*)(sm + cur + 8192);
    bf16x8 af[4];
#pragma unroll
    for (int mt = 0; mt < 4; ++mt)
      af[mt] = *(const bf16x8*)&As[(wm + 16 * mt + lr) * 32 + 8 * quad];
#pragma unroll
    for (int nt = 0; nt < 4; ++nt) {
      bf16x8 bf = *(const bf16x8*)&Bs[(wn + 16 * nt + lr) * 32 + 8 * quad];
#pragma unroll
      for (int mt = 0; mt < 4; ++mt)
        acc[mt][nt] = __builtin_amdgcn_mfma_f32_16x16x32_bf16(af[mt], bf,
                                                              acc[mt][nt], 0, 0, 0);
    }
    if (k + 1 < 24) asm volatile("s_waitcnt vmcnt(0)" ::: "memory");
    __builtin_amdgcn_s_barrier();
    __builtin_amdgcn_sched_barrier(0);  // no ds_read hoisting above barrier
  }

  __syncthreads();  // As/Bs dead; Ts region now safe to write

  const int b_ = m0 >> 11;           // batch (128-row tile never crosses b)
  const int hbase = n0 >> 6;         // first head of this tile
  const int sgbase = (m0 & 2047) >> 5;  // first 32-row s-block

  if (mode < 2) {
    // Ts[s_local][d_local], stride 136
    const float osc = (mode == 0) ? 0.18033688011f : 1.0f;  // 0.125*log2(e)
#pragma unroll
    for (int mt = 0; mt < 4; ++mt)
#pragma unroll
      for (int nt = 0; nt < 4; ++nt) {
        int n = wn + 16 * nt + lr;
        int mb = wm + 16 * mt + 4 * quad;
#pragma unroll
        for (int r = 0; r < 4; ++r)
          Ts[(mb + r) * 136 + n] = f2b(acc[mt][nt][r] * osc);
      }
    __syncthreads();
    unsigned short* O = (mode == 0) ? QF : KF;
    const int ks = tid >> 6, lane2 = tid & 63;
    const int mrow = lane2 & 31, hb = lane2 >> 5;
#pragma unroll
    for (int c = 0; c < 8; ++c) {
      int hl = c >> 2, sblk = c & 3;
      int bh = b_ * HH + hbase + hl;
      bf16x8 vv = *(const bf16x8*)&Ts[(sblk * 32 + mrow) * 136 + hl * 64 +
                                      ks * 16 + hb * 8];
      *(bf16x8*)(O + ((size_t)bh * 64 + sgbase + sblk) * 2048 + tid * 8) = vv;
    }
  } else {
    // Ts[d_local][s_local], stride 136 (b64 writes: 4 consecutive s)
#pragma unroll
    for (int mt = 0; mt < 4; ++mt)
#pragma unroll
      for (int nt = 0; nt < 4; ++nt) {
        int n = wn + 16 * nt + lr;
        int mb = wm + 16 * mt + 4 * quad;
        *(us4*)&Ts[n * 136 + mb] =
            f2b4(acc[mt][nt][0], acc[mt][nt][1], acc[mt][nt][2], acc[mt][nt][3]);
      }
    __syncthreads();
    const int ntv = tid >> 7, ks2 = (tid >> 6) & 1, lane2 = tid & 63;
#pragma unroll
    for (int c = 0; c < 8; ++c) {
      int hl = c >> 2, sblk = c & 3;
      int bh = b_ * HH + hbase + hl;
      bf16x8 vv = *(const bf16x8*)&Ts[(hl * 64 + ntv * 32 + (lane2 & 31)) * 136 +
                                      sblk * 32 + ks2 * 16 + (lane2 >> 5) * 8];
      *(bf16x8*)(VF + ((size_t)bh * 64 + sgbase + sblk) * 2048 + tid * 8) = vv;
    }
  }
#undef STAGEP
}

// ---------------------------------------------------------------------------
// Flash attention — r4/r8 version verbatim (best measured: 75.0 us).
// 32x32x16 MFMA, barrier-free main loop, fragment-major global loads,
// software-pipelined tile pairs, P in registers (cvt_pk + permlane32_swap),
// no-max softmax (scale pre-folded into Q), XCD swizzle (6 bh per XCD).
// ---------------------------------------------------------------------------
struct KV {
  bf16x8 k[4];
  bf16x8 v[4];
};

__global__ __launch_bounds__(256) void attn(
    const unsigned short* __restrict__ QF, const unsigned short* __restrict__ KF,
    const unsigned short* __restrict__ VF, unsigned short* __restrict__ cc) {
  // LDS: Osh (epilogue only) + Ls/Linv
  __shared__ __align__(16) char smem[19200];
  float (*Osh)[64][36] = (float (*)[64][36])smem;                    // 18432 B
  float (*Ls)[2][32] = (float (*)[2][32])(smem + 18432);             // 512 B
  float (*Linv)[32] = (float (*)[32])(smem + 18944);                 // 256 B

  const int tid = threadIdx.x;
  const int lane = tid & 63, w_ = tid >> 6;
  const int wq = w_ & 1, wk = w_ >> 1;
  const int m32 = lane & 31, h = lane >> 5;
  // bijective XCD swizzle (1536 blocks, 1536%8==0): XCD k owns bh 6k..6k+5
  const int lin = blockIdx.y * 32 + blockIdx.x;
  const int nlin = (lin & 7) * 192 + (lin >> 3);
  const int bh = nlin >> 5;
  const int q0 = (nlin & 31) * 64;
  const size_t perbh = (size_t)SS * DEPTH;

  const unsigned short* qfb = QF + (size_t)bh * perbh;
  const unsigned short* kfb = KF + (size_t)bh * perbh + (size_t)wk * 2048 + lane * 8;
  const unsigned short* vfb = VF + (size_t)bh * perbh + (size_t)wk * 2048 + lane * 8;

  bf16x8 qf[4];
  {
    const unsigned short* p = qfb + (size_t)((q0 >> 5) + wq) * 2048 + lane * 8;
#pragma unroll
    for (int ks = 0; ks < 4; ++ks) qf[ks] = *(const bf16x8*)(p + ks * 512);
  }

  f32x16 o[2];
#pragma unroll
  for (int nt = 0; nt < 2; ++nt)
#pragma unroll
    for (int r = 0; r < 16; ++r) o[nt][r] = 0.f;
  float l_lane = 0.f;

#define LOADKV(tile, dst)                                                    \
  do {                                                                       \
    const unsigned short* kp_ = kfb + (size_t)(tile) * 4096;                 \
    const unsigned short* vp_ = vfb + (size_t)(tile) * 4096;                 \
    _Pragma("unroll") for (int x_ = 0; x_ < 4; ++x_) {                       \
      (dst).k[x_] = *(const bf16x8*)(kp_ + x_ * 512);                        \
      (dst).v[x_] = *(const bf16x8*)(vp_ + x_ * 512);                        \
    }                                                                        \
  } while (0)

  // QK^T for one tile: st[4g+i] = S^T[key = i+8g+4h][q = m32]
#define QKCOMP(kv, st)                                                       \
  do {                                                                       \
    _Pragma("unroll") for (int r_ = 0; r_ < 16; ++r_) (st)[r_] = 0.f;        \
    __builtin_amdgcn_s_setprio(1);                                           \
    _Pragma("unroll") for (int ks_ = 0; ks_ < 4; ++ks_)                      \
        (st) = __builtin_amdgcn_mfma_f32_32x32x16_bf16((kv).k[ks_], qf[ks_], \
                                                       (st), 0, 0, 0);       \
    __builtin_amdgcn_s_setprio(0);                                           \
  } while (0)

  // exp2 + pack to bf16 PV A-fragments (cvt_pk + permlane32_swap), then PV.
  // pa[ks2][j] = P[q=m32][key = 16*ks2 + 8*h + j].
#define EXPPV(st, kv)                                                        \
  do {                                                                       \
    float e_[16];                                                            \
    _Pragma("unroll") for (int r_ = 0; r_ < 16; ++r_) e_[r_] = fexp2((st)[r_]); \
    _Pragma("unroll") for (int g_ = 0; g_ < 4; ++g_)                         \
        l_lane += (e_[4 * g_ + 0] + e_[4 * g_ + 1]) +                        \
                  (e_[4 * g_ + 2] + e_[4 * g_ + 3]);                         \
    unsigned w00 = cvtpk(e_[0], e_[1]), w01 = cvtpk(e_[2], e_[3]);           \
    unsigned w10 = cvtpk(e_[4], e_[5]), w11 = cvtpk(e_[6], e_[7]);           \
    unsigned w20 = cvtpk(e_[8], e_[9]), w21 = cvtpk(e_[10], e_[11]);         \
    unsigned w30 = cvtpk(e_[12], e_[13]), w31 = cvtpk(e_[14], e_[15]);       \
    u32x2 r0 = permswap(w00, w10);                                           \
    u32x2 r1 = permswap(w01, w11);                                           \
    u32x2 r2 = permswap(w20, w30);                                           \
    u32x2 r3 = permswap(w21, w31);                                           \
    u32x4 paw0, paw1;                                                        \
    paw0.x = r0.x; paw0.y = r1.x; paw0.z = r0.y; paw0.w = r1.y;              \
    paw1.x = r2.x; paw1.y = r3.x; paw1.z = r2.y; paw1.w = r3.y;              \
    bf16x8 pa0 = __builtin_bit_cast(bf16x8, paw0);                           \
    bf16x8 pa1 = __builtin_bit_cast(bf16x8, paw1);                           \
    __builtin_amdgcn_s_setprio(1);                                           \
    o[0] = __builtin_amdgcn_mfma_f32_32x32x16_bf16(pa0, (kv).v[0], o[0],     \
                                                   0, 0, 0);                 \
    o[1] = __builtin_amdgcn_mfma_f32_32x32x16_bf16(pa0, (kv).v[2], o[1],     \
                                                   0, 0, 0);                 \
    o[0] = __builtin_amdgcn_mfma_f32_32x32x16_bf16(pa1, (kv).v[1], o[0],     \
                                                   0, 0, 0);                 \
    o[1] = __builtin_amdgcn_mfma_f32_32x32x16_bf16(pa1, (kv).v[3], o[1],     \
                                                   0, 0, 0);                 \
    __builtin_amdgcn_s_setprio(0);                                           \
  } while (0)

  KV b0, b1;
  f32x16 st0, st1;
  LOADKV(0, b0);
  LOADKV(1, b1);
  for (int t = 0; t < 32; t += 2) {
    QKCOMP(b0, st0);
    QKCOMP(b1, st1);          // independent MFMAs fill the pipe...
    EXPPV(st0, b0);           // ...while b0's exp/pack runs on the VALU
    if (t + 2 < 32) LOADKV(t + 2, b0);  // b0 fully consumed
    EXPPV(st1, b1);           // covers PV(b0) MFMA latency
    if (t + 3 < 32) LOADKV(t + 3, b1);
  }

  // ---- epilogue: combine key-halves, normalize, store ----
  l_lane += __shfl_xor(l_lane, 32);
  if (h == 0) Ls[wq][wk][m32] = l_lane;
  __syncthreads();  // all waves out of main loop
  if (wk == 1) {
#pragma unroll
    for (int nt = 0; nt < 2; ++nt)
#pragma unroll
      for (int g = 0; g < 4; ++g) {
        float4 t = make_float4(o[nt][4 * g], o[nt][4 * g + 1], o[nt][4 * g + 2],
                               o[nt][4 * g + 3]);
        *(float4*)&Osh[wq][32 * nt + m32][8 * g + 4 * h] = t;
      }
  } else if (tid < 64) {
    int qq = tid & 31, ww = tid >> 5;
    Linv[ww][qq] = 1.f / (Ls[ww][0][qq] + Ls[ww][1][qq]);
  }
  __syncthreads();
  if (wk == 0) {
    const int b_ = bh / HH, h_ = bh % HH;
#pragma unroll
    for (int g = 0; g < 4; ++g) {
      float4 li = *(const float4*)&Linv[wq][8 * g + 4 * h];
      float lia[4] = {li.x, li.y, li.z, li.w};
#pragma unroll
      for (int nt = 0; nt < 2; ++nt) {
        float4 ot = *(const float4*)&Osh[wq][32 * nt + m32][8 * g + 4 * h];
        float oa[4] = {ot.x, ot.y, ot.z, ot.w};
#pragma unroll
        for (int r = 0; r < 4; ++r) {
          int qg = q0 + 32 * wq + 8 * g + 4 * h + r;
          float val = (o[nt][4 * g + r] + oa[r]) * lia[r];
          cc[((size_t)b_ * SS + qg) * DD + h_ * DEPTH + 32 * nt + m32] = f2b(val);
        }
      }
    }
  }
}

// ---------------------------------------------------------------------------
// Output projection: out = cc @ wo.T + bo (fp32 out), BK=32, double-buffered
// pipeline (same T3 2-phase structure as proj_qkv). LDS 32 KB.
// Same XCD swizzle (384 blocks, 384%8==0).
// ---------------------------------------------------------------------------
__global__ __launch_bounds__(256) void proj_out(
    const unsigned short* __restrict__ cc, const unsigned short* __restrict__ wob,
    const float* __restrict__ bo, float* __restrict__ out) {
  __shared__ __align__(16) char smo[32768];

  const int tid = threadIdx.x;
  const int lane = tid & 63, w_ = tid >> 6;
  const int lr = lane & 15, quad = lane >> 4;
  const int wm = (w_ & 1) * 64, wn = (w_ >> 1) * 64;
  const int lin = blockIdx.y * 64 + blockIdx.x;
  const int nlin = (lin & 7) * 48 + (lin >> 3);
  const int m0 = (nlin / 6) * 128, n0 = (nlin % 6) * 128;
  const int grow = lane >> 2, gcol = (lane & 3) * 8;

  f32x4 acc[4][4];
#pragma unroll
  for (int mt = 0; mt < 4; ++mt)
#pragma unroll
    for (int nt = 0; nt < 4; ++nt) acc[mt][nt] = (f32x4){0.f, 0.f, 0.f, 0.f};

#define STAGEO(k0, bufo)                                                     \
  do {                                                                       \
    _Pragma("unroll") for (int i_ = 0; i_ < 2; ++i_) {                       \
      int c_ = 4 * i_ + w_;                                                  \
      int row_ = c_ * 16 + grow;                                             \
      gl16(cc + (size_t)(m0 + row_) * DD + (k0) + gcol,                      \
           smo + (bufo) + c_ * 1024);                                        \
      gl16(wob + (size_t)(n0 + row_) * DD + (k0) + gcol,                     \
           smo + (bufo) + 8192 + c_ * 1024);                                 \
    }                                                                        \
  } while (0)

  STAGEO(0, 0);
  asm volatile("s_waitcnt vmcnt(0)" ::: "memory");
  __builtin_amdgcn_s_barrier();
  __builtin_amdgcn_sched_barrier(0);

  for (int k = 0; k < 24; ++k) {
    const int cur = (k & 1) << 14;
    if (k + 1 < 24) STAGEO((k + 1) * 32, cur ^ 16384);
    const unsigned short* As = (const unsigned short*)(smo + cur);
    const unsigned short* Bs = (const unsigned short*)(smo + cur + 8192);
    bf16x8 af[4];
#pragma unroll
    for (int mt = 0; mt < 4; ++mt)
      af[mt] = *(const bf16x8*)&As[(wm + 16 * mt + lr) * 32 + 8 * quad];
#pragma unroll
    for (int nt = 0; nt < 4; ++nt) {
      bf16x8 bf = *(const bf16x8*)&Bs[(wn + 16 * nt + lr) * 32 + 8 * quad];
#pragma unroll
      for (int mt = 0; mt < 4; ++mt)
        acc[mt][nt] = __builtin_amdgcn_mfma_f32_16x16x32_bf16(af[mt], bf,
                                                              acc[mt][nt], 0, 0, 0);
    }
    if (k + 1 < 24) asm volatile("s_waitcnt vmcnt(0)" ::: "memory");
    __builtin_amdgcn_s_barrier();
    __builtin_amdgcn_sched_barrier(0);
  }

#pragma unroll
  for (int mt = 0; mt < 4; ++mt)
#pragma unroll
    for (int nt = 0; nt < 4; ++nt) {
      int n = n0 + wn + 16 * nt + lr;
      float bias = bo[n];
#pragma unroll
      for (int r = 0; r < 4; ++r) {
        int m = m0 + wm + 16 * mt + 4 * quad + r;
        out[(size_t)m * DD + n] = acc[mt][nt][r] + bias;
      }
    }
#undef STAGEO
}

extern "C" void kernel_launch(void* const* d_in, const int* in_sizes, int n_in,
                              void* d_out, int out_size, void* d_ws,
                              size_t ws_size, hipStream_t stream) {
  const float* v = (const float*)d_in[0];
  const float* k = (const float*)d_in[1];
  const float* q = (const float*)d_in[2];
  const float* wq = (const float*)d_in[3];
  const float* wk = (const float*)d_in[4];
  const float* wv = (const float*)d_in[5];
  const float* wo = (const float*)d_in[6];
  const float* bo = (const float*)d_in[7];
  float* out = (float*)d_out;

  const size_t per = (size_t)BB * HH * SS * DEPTH;  // 6291456
  unsigned short* QF = (unsigned short*)d_ws;
  unsigned short* KF = QF + per;
  unsigned short* VF = KF + per;
  unsigned short* cc = VF + per;
  unsigned short* qb = cc + per;
  unsigned short* kb = qb + per;
  unsigned short* vb = kb + per;
  unsigned short* wqb = vb + per;
  unsigned short* wkb = wqb + WSZ;
  unsigned short* wvb = wkb + WSZ;
  unsigned short* wob = wvb + WSZ;

  // exact grid: 3*6144 activation blocks + 4*576 weight blocks
  prep<<<dim3(20736), 256, 0, stream>>>(q, k, v, wq, wk, wv, wo, qb, kb, vb,
                                        wqb, wkb, wvb, wob);

  dim3 g1(M_TOTAL / 128, DD / 128, 3);
  proj_qkv<<<g1, 256, 0, stream>>>(qb, kb, vb, wqb, wkb, wvb, QF, KF, VF);

  dim3 g2(SS / 64, BB * HH);
  attn<<<g2, 256, 0, stream>>>(QF, KF, VF, cc);

  dim3 g3(M_TOTAL / 128, DD / 128);
  proj_out<<<g3, 256, 0, stream>>>(cc, wob, bo, out);
}